// Round 4
// baseline (158.584 us; speedup 1.0000x reference)
//
#include <hip/hip_runtime.h>

// TINShift: out[n,t,c,hw] = x[n, t + shift[n, c/32], c, hw] if 0<=t+s<T else 0.
// N=8, T=16, C=256, HW=3136 (784 float4), G=8. Pure streaming gather.
//
// Round 4: identical to Round 3 EXCEPT nontemporal load/store reverted to
// plain accesses (isolation experiment — R3 regressed 141->151 with nt+
// restructure confounded; theory: nt's L2 bypass defeats burst absorption,
// structure is neutral).
//
// Decomposition: one block per (n,c) pair covering ALL T=16 rows.
//   - shift lookup: one wave-uniform scalar load per block.
//   - 16*784 = 12544 float4 = exactly 49 full 256-thread iterations (no tail).
//   - src index = dst index + s * (C*HW4); validity is the per-lane
//     predicate ((unsigned)(t+s) < T), wave-uniform within a row.
// Grid: N*C = 2048 blocks = 8 blocks/CU * 4 waves = 32 waves/CU (max occ).

typedef float f32x4 __attribute__((ext_vector_type(4)));

#define TIN_N   8
#define TIN_T   16
#define TIN_C   256
#define TIN_G   8
#define TIN_HW4 784                       // 3136 floats / 4
#define T_STRIDE4 (TIN_C * TIN_HW4)       // float4 distance between t and t+1
#define BLK_ELEMS (TIN_T * TIN_HW4)       // 12544 float4 per (n,c) block
#define BLK_ITERS (BLK_ELEMS / 256)       // 49, exact

__global__ __launch_bounds__(256) void tin_shift_kernel(
    const f32x4* __restrict__ x4,
    const int*   __restrict__ shift,
    f32x4*       __restrict__ out4)
{
    const int nc = blockIdx.x;                 // n*C + c, 0..2047
    const int c  = nc & (TIN_C - 1);
    const int n  = nc >> 8;
    const int s  = shift[n * TIN_G + (c >> 5)];   // wave-uniform scalar load

    // float4 index of (n, t=0, c, hw=0) in both x and out
    const size_t base = ((size_t)n * (TIN_T * TIN_C) + c) * TIN_HW4;
    const long   soff = (long)s * T_STRIDE4;       // src = dst + soff

    const int tid = threadIdx.x;

    #pragma unroll 7
    for (int it = 0; it < BLK_ITERS; ++it) {
        const int f  = it * 256 + tid;             // 0 .. 12543
        const int t  = f / TIN_HW4;                // magic-mul, f < 2^24
        const int hw = f - t * TIN_HW4;
        const size_t di = base + (size_t)t * T_STRIDE4 + (size_t)hw;

        f32x4 v = (f32x4){0.f, 0.f, 0.f, 0.f};
        if ((unsigned)(t + s) < TIN_T) {
            v = x4[(long)di + soff];
        }
        out4[di] = v;
    }
}

extern "C" void kernel_launch(void* const* d_in, const int* in_sizes, int n_in,
                              void* d_out, int out_size, void* d_ws, size_t ws_size,
                              hipStream_t stream)
{
    const f32x4* x4    = (const f32x4*)d_in[0];
    const int*   shift = (const int*)d_in[1];
    f32x4*       out4  = (f32x4*)d_out;

    tin_shift_kernel<<<TIN_N * TIN_C, 256, 0, stream>>>(x4, shift, out4);
}

// Round 5
// 129.919 us; speedup vs baseline: 1.2206x; 1.2206x over previous
//
#include <hip/hip_runtime.h>

// TINShift: out[n,t,c,hw] = x[n, t + shift[n, c/32], c, hw] if 0<=t+s<T else 0.
// N=8, T=16, C=256, HW=3136 (784 float4), G=8. Pure streaming gather.
//
// Round 5 = Round 1 structure (one block per (n,t,c) row — proven 141.4 us;
// the (n,c)-block restructure regressed 17 us due to worse HBM page locality)
// + nontemporal load/store (isolated R3-vs-R4: nt = +8 us within same
// structure; both streams are touched exactly once, 411 MB each > L3).

typedef float f32x4 __attribute__((ext_vector_type(4)));

#define TIN_N   8
#define TIN_T   16
#define TIN_C   256
#define TIN_G   8
#define TIN_HW4 784                       // 3136 floats / 4

__global__ __launch_bounds__(256) void tin_shift_kernel(
    const f32x4* __restrict__ x4,
    const int*   __restrict__ shift,
    f32x4*       __restrict__ out4)
{
    // One block per (n, t, c) row; consecutive blocks = consecutive rows in
    // memory -> adjacent resident blocks form large contiguous HBM bursts.
    const int row = blockIdx.x;                 // 0 .. N*T*C-1 (32768)
    const int c   = row & (TIN_C - 1);          // C = 256 (pow2)
    const int t   = (row >> 8) & (TIN_T - 1);   // T = 16  (pow2)
    const int n   = row >> 12;

    const int s  = shift[n * TIN_G + (c >> 5)]; // wave-uniform scalar load
    const int ts = t + s;

    f32x4* dst = out4 + (size_t)row * TIN_HW4;
    const int tid = threadIdx.x;

    if ((unsigned)ts < TIN_T) {
        const f32x4* src = x4 + ((size_t)row + (long)s * TIN_C) * TIN_HW4;
        #pragma unroll
        for (int i = tid; i < TIN_HW4; i += 256) {
            __builtin_nontemporal_store(__builtin_nontemporal_load(&src[i]), &dst[i]);
        }
    } else {
        const f32x4 z = (f32x4){0.f, 0.f, 0.f, 0.f};
        #pragma unroll
        for (int i = tid; i < TIN_HW4; i += 256) {
            __builtin_nontemporal_store(z, &dst[i]);
        }
    }
}

extern "C" void kernel_launch(void* const* d_in, const int* in_sizes, int n_in,
                              void* d_out, int out_size, void* d_ws, size_t ws_size,
                              hipStream_t stream)
{
    const f32x4* x4    = (const f32x4*)d_in[0];
    const int*   shift = (const int*)d_in[1];
    f32x4*       out4  = (f32x4*)d_out;

    const int rows = TIN_N * TIN_T * TIN_C;     // 32768 blocks
    tin_shift_kernel<<<rows, 256, 0, stream>>>(x4, shift, out4);
}